// Round 11
// baseline (129.598 us; speedup 1.0000x reference)
//
#include <hip/hip_runtime.h>
#include <math.h>
#include <float.h>

// b=8, c=64, H=W=64, KS=8 -> P = 57*57 = 3249.
// Stage 1 per (b,c): G[m,n] = <patch_m, patch_n> over P; corr = G/(sqrt(diag)sqrt(diag)P);
//   sort 64 m per column n desc; ranks {1,9,16,24,32,40,48,55,63} -> xp[b,c,576].
// Stage 2 per b: corr2[p,q] = sum_c Xn[c,p]Xn[c,q]/64; sort 576 p per q desc; 115 ranks.
//
// R11: R10's LDS block-exchange was correct in dataflow but missing compiler
//      ordering: per-lane alias analysis can hoist the partner ds_read above the
//      ds_write (cross-lane deps are invisible) -> inf. Fix: wave_barrier()
//      fences around each exchange stage (HW DS pipe is in-order per wave;
//      only the compiler needed restraining). k1/k2 = R9 known-good.

#define IMGS 65

// ---- DPP helpers (compile-time ctrl; LDS-pipe-free cross-lane) ----
template<int CTRL, int RM>
__device__ __forceinline__ float dpp_add(float x) {
    int o = __builtin_amdgcn_update_dpp(0, __float_as_int(x), CTRL, RM, 0xf, true);
    return x + __int_as_float(o);
}
// inclusive wave64 prefix sum
__device__ __forceinline__ float wscan_add(float x) {
    x = dpp_add<0x111, 0xf>(x);
    x = dpp_add<0x112, 0xf>(x);
    x = dpp_add<0x114, 0xf>(x);
    x = dpp_add<0x118, 0xf>(x);
    x = dpp_add<0x142, 0xa>(x);
    x = dpp_add<0x143, 0xc>(x);
    return x;
}
template<int CTRL>
__device__ __forceinline__ float dpp_perm(float x) {
    int o = __builtin_amdgcn_update_dpp(__float_as_int(x), __float_as_int(x), CTRL, 0xf, 0xf, false);
    return __int_as_float(o);
}
#define QP_XOR1 0xB1   // quad_perm [1,0,3,2]
#define QP_XOR2 0x4E   // quad_perm [2,3,0,1]

__host__ __device__ constexpr int offF(int dj) { return dj * (17 - dj) / 2; }       // 36
__host__ __device__ constexpr int offB(int dj) { return (dj - 1) * (16 - dj) / 2; } // 28

// ---------------- k1: fused stage-1, pair-symmetric, canonical-G ----------------
// grid = 512 (bc), block = 512 (8 waves; wave wv handles row-shift d = wv)
__global__ __launch_bounds__(512) void k1(const float* __restrict__ x,
                                          float* __restrict__ xp) {
    __shared__ float img[64 * IMGS];   // 16.6 KB
    __shared__ float G[64 * IMGS];     // canonical: G[m*65+n], m<=n

    const int t = threadIdx.x;
    const int bc = blockIdx.x;
    const float* src = x + (size_t)bc * 4096;

    #pragma unroll
    for (int k = 0; k < 2; ++k) {
        int i4 = t + k * 512;
        float4 v = ((const float4*)src)[i4];
        int fl = i4 * 4, row = fl >> 6, col = fl & 63;
        float* dd = &img[row * IMGS + col];
        dd[0] = v.x; dd[1] = v.y; dd[2] = v.z; dd[3] = v.w;
    }
    __syncthreads();

    const int wv = t >> 6, lane = t & 63;
    const int d = wv;                            // 0..7
    const int a = lane;
    const bool av = (a + d <= 63);
    const int a1 = min(a + d, 63);
    const float* r0 = &img[a * IMGS];
    const float* r1 = &img[a1 * IMGS];

    // ---- FMA phase: wf[k]=sum_{u<57} r0[u]*r1[u+k], wb[k]=sum r1[u]*r0[u+k] ----
    float wf[8] = {0,0,0,0,0,0,0,0}, wb[8] = {0,0,0,0,0,0,0,0};
    float sf[8], sb[8], hf[7], hb[7];
    #pragma unroll
    for (int k = 0; k < 7; ++k) { sf[k] = r1[k]; sb[k] = r0[k]; hf[k] = sf[k]; hb[k] = sb[k]; }
    #pragma unroll
    for (int c = 0; c < 7; ++c) {
        #pragma unroll
        for (int j = 0; j < 8; ++j) {
            const int u = c * 8 + j;
            sf[(j + 7) & 7] = r1[u + 7];
            sb[(j + 7) & 7] = r0[u + 7];
            const float f0 = sb[j & 7];          // r0[u]
            const float g0 = sf[j & 7];          // r1[u]
            #pragma unroll
            for (int k = 0; k < 8; ++k) wf[k] = fmaf(f0, sf[(j + k) & 7], wf[k]);
            #pragma unroll
            for (int k = 1; k < 8; ++k) wb[k] = fmaf(g0, sb[(j + k) & 7], wb[k]);
        }
    }
    {   // u = 56
        sf[7] = r1[63]; sb[7] = r0[63];
        const float f0 = sb[0], g0 = sf[0];
        #pragma unroll
        for (int k = 0; k < 8; ++k) wf[k] = fmaf(f0, sf[k], wf[k]);
        #pragma unroll
        for (int k = 1; k < 8; ++k) wb[k] = fmaf(g0, sb[k], wb[k]);
    }
    // tails: sf[k] = r1[56+k], sb[k] = r0[56+k]; heads: hf/hb

    const float msk = av ? 1.0f : 0.0f;
    const bool wr = (lane >= 56) && (lane <= 63 - d);
    const int ki = lane - 56;

    // ======== FORWARD set (registers freed before backward set) ========
    {
        float Wf[36];
        #pragma unroll
        for (int dj = 0; dj < 8; ++dj) {
            float a0 = wf[dj];
            Wf[offF(dj)] = a0;
            #pragma unroll
            for (int st = 1; st < 8 - dj; ++st) {
                a0 += sb[st] * sf[st + dj] - hb[st - 1] * hf[st - 1 + dj];
                Wf[offF(dj) + st] = a0;
            }
        }
        #pragma unroll
        for (int i = 0; i < 36; ++i) Wf[i] = wscan_add(Wf[i] * msk);
        #pragma unroll
        for (int dj = 0; dj < 8; ++dj) {
            float su[8], S[8];
            #pragma unroll
            for (int st = 0; st < 8 - dj; ++st) su[st] = __shfl_up(Wf[offF(dj) + st], 57, 64);
            #pragma unroll
            for (int st = 0; st < 8 - dj; ++st)
                S[st] = Wf[offF(dj) + st] - (lane >= 57 ? su[st] : 0.0f);
            #pragma unroll
            for (int st = 0; st < 8 - dj; ++st)
                if (wr) G[(ki * 8 + st) * IMGS + ((ki + d) * 8 + st + dj)] = S[st];
        }
    }
    // ======== BACKWARD set ========
    if (d > 0) {
        float Wb[28];
        #pragma unroll
        for (int dj = 1; dj < 8; ++dj) {
            float a0 = wb[dj];
            Wb[offB(dj)] = a0;
            #pragma unroll
            for (int st = 1; st < 8 - dj; ++st) {
                a0 += sf[st] * sb[st + dj] - hf[st - 1] * hb[st - 1 + dj];
                Wb[offB(dj) + st] = a0;
            }
        }
        #pragma unroll
        for (int i = 0; i < 28; ++i) Wb[i] = wscan_add(Wb[i] * msk);
        #pragma unroll
        for (int dj = 1; dj < 8; ++dj) {
            float su[7], S[7];
            #pragma unroll
            for (int st = 0; st < 8 - dj; ++st) su[st] = __shfl_up(Wb[offB(dj) + st], 57, 64);
            #pragma unroll
            for (int st = 0; st < 8 - dj; ++st)
                S[st] = Wb[offB(dj) + st] - (lane >= 57 ? su[st] : 0.0f);
            #pragma unroll
            for (int st = 0; st < 8 - dj; ++st)
                if (wr) G[(ki * 8 + st + dj) * IMGS + ((ki + d) * 8 + st)] = S[st];
        }
    }
    __syncthreads();

    // ---- normalize + batched sort64 (wave wv: columns wv*8..wv*8+7) ----
    const int m = lane;
    const float invm = 1.0f / fmaxf(sqrtf(G[m * 66]), 1e-12f);
    const float sc = 1.0f / 3249.0f;
    const int c0 = wv * 8;
    float v[8];
    #pragma unroll
    for (int cc = 0; cc < 8; ++cc) {
        const int col = c0 + cc;
        const int addr = (m <= col) ? m * IMGS + col : col * IMGS + m;   // symmetric read
        const float invc = __shfl(invm, col, 64);
        v[cc] = G[addr] * invm * invc * sc;
    }
    #pragma unroll
    for (int kk = 2; kk <= 64; kk <<= 1) {
        #pragma unroll
        for (int j = kk >> 1; j > 0; j >>= 1) {
            const bool upper = (lane & j) != 0;
            const bool dir0  = (lane & kk) == 0;
            const bool keep_max = dir0 ^ upper;
            float o[8];
            #pragma unroll
            for (int cc = 0; cc < 8; ++cc) {
                if (j == 1)      o[cc] = dpp_perm<QP_XOR1>(v[cc]);
                else if (j == 2) o[cc] = dpp_perm<QP_XOR2>(v[cc]);
                else             o[cc] = __shfl_xor(v[cc], j, 64);
            }
            #pragma unroll
            for (int cc = 0; cc < 8; ++cc)
                v[cc] = keep_max ? fmaxf(v[cc], o[cc]) : fminf(v[cc], o[cc]);
        }
    }
    // ranks2 = {1,9,16,24,32,40,48,55,63}
    int ridx = -1;
    if      (lane ==  1) ridx = 0; else if (lane ==  9) ridx = 1; else if (lane == 16) ridx = 2;
    else if (lane == 24) ridx = 3; else if (lane == 32) ridx = 4; else if (lane == 40) ridx = 5;
    else if (lane == 48) ridx = 6; else if (lane == 55) ridx = 7; else if (lane == 63) ridx = 8;
    if (ridx >= 0) {
        float* dst = xp + (size_t)bc * 576 + ridx * 64 + c0;
        *(float4*)&dst[0] = make_float4(v[0], v[1], v[2], v[3]);
        *(float4*)&dst[4] = make_float4(v[4], v[5], v[6], v[7]);
    }
}

// ---------------- k2: stage-2 inverse channel norms ----------------
// grid = 8, block = 576
__global__ __launch_bounds__(576) void k2(const float* __restrict__ xp,
                                          float* __restrict__ ipn) {
    const int b = blockIdx.x, p = threadIdx.x;
    const float* base = xp + (size_t)b * 36864 + p;
    float s = 0.f;
    #pragma unroll
    for (int c = 0; c < 64; ++c) { float v = base[c * 576]; s = fmaf(v, v, s); }
    ipn[b * 576 + p] = 1.0f / fmaxf(sqrtf(s), 1e-12f);
}

// ---------------- k3: stage-2 corr columns + register bitonic sort + ranks ----------
// grid = 8*144 (4 q per block; wave wv sorts column q0+wv), block = 256
// Cross-lane jl>=4 via per-wave LDS block exchange, fenced with wave_barrier.
__global__ __launch_bounds__(256) void k3(const float* __restrict__ xp,
                                          const float* __restrict__ ipn,
                                          float* __restrict__ out) {
    __shared__ __align__(16) float sbuf[4][580];
    __shared__ float rankbuf[115 * 4];
    __shared__ __align__(16) float exbuf[4][64 * 20];   // 20 KB: wave-private exchange
    const int t = threadIdx.x;
    const int b = blockIdx.x / 144, qg = blockIdx.x % 144;
    const int q0 = qg * 4;
    const float* __restrict__ xb  = xp  + (size_t)b * 36864;
    const float* __restrict__ ipb = ipn + (size_t)b * 576;

    // ---- phase 1: normalized corr2 columns for 4 q's ----
    {
        float iq[4];
        #pragma unroll
        for (int qq = 0; qq < 4; ++qq) iq[qq] = ipb[q0 + qq] * 0.015625f;   // /64
        for (int p = t; p < 576; p += 256) {
            float a0 = 0.f, a1 = 0.f, a2 = 0.f, a3 = 0.f;
            #pragma unroll 8
            for (int c = 0; c < 64; ++c) {
                const float xv = xb[c * 576 + p];              // coalesced vector load
                const int qb = c * 576 + q0;
                a0 = fmaf(xv, xb[qb + 0], a0);                 // uniform -> scalar loads
                a1 = fmaf(xv, xb[qb + 1], a1);
                a2 = fmaf(xv, xb[qb + 2], a2);
                a3 = fmaf(xv, xb[qb + 3], a3);
            }
            const float ip = ipb[p];
            sbuf[0][p] = a0 * ip * iq[0];
            sbuf[1][p] = a1 * ip * iq[1];
            sbuf[2][p] = a2 * ip * iq[2];
            sbuf[3][p] = a3 * ip * iq[3];
        }
    }
    __syncthreads();

    // ---- phase 2: wave wv sorts its column (1024-pad register bitonic) ----
    const int wv = t >> 6, lane = t & 63;
    float* const ex = &exbuf[wv][0];
    float v[16];
    if (lane < 36) {
        const float* sb2 = &sbuf[wv][0];
        #pragma unroll
        for (int k2i = 0; k2i < 4; ++k2i) {
            float4 f = *(const float4*)&sb2[lane * 16 + k2i * 4];
            v[k2i * 4 + 0] = f.x; v[k2i * 4 + 1] = f.y;
            v[k2i * 4 + 2] = f.z; v[k2i * 4 + 3] = f.w;
        }
    } else {
        #pragma unroll
        for (int r = 0; r < 16; ++r) v[r] = -FLT_MAX;
    }

    #pragma unroll
    for (int kk = 2; kk <= 1024; kk <<= 1) {
        #pragma unroll
        for (int j = kk >> 1; j > 0; j >>= 1) {
            if (j >= 64) {
                // ---- LDS block exchange: partner lane^jl, whole 16-run b128 ----
                // Cross-lane dep is invisible to per-lane alias analysis; the
                // wave_barrier fences stop the compiler reordering ds ops across
                // stages (HW DS pipe is in-order within a wave).
                const int jl = j >> 4;                       // 4,8,16,32
                const bool upper = (lane & jl) != 0;
                const bool dir0  = (lane & (kk >> 4)) == 0;
                const bool keep_max = dir0 ^ upper;
                #pragma unroll
                for (int k2i = 0; k2i < 4; ++k2i)
                    *(float4*)&ex[lane * 20 + k2i * 4] =
                        make_float4(v[k2i*4], v[k2i*4+1], v[k2i*4+2], v[k2i*4+3]);
                __builtin_amdgcn_wave_barrier();             // writes before reads
                const int pb = (lane ^ jl) * 20;
                float4 o4[4];
                #pragma unroll
                for (int k2i = 0; k2i < 4; ++k2i) o4[k2i] = *(const float4*)&ex[pb + k2i * 4];
                __builtin_amdgcn_wave_barrier();             // reads before next stage's writes
                #pragma unroll
                for (int k2i = 0; k2i < 4; ++k2i) {
                    v[k2i*4+0] = keep_max ? fmaxf(v[k2i*4+0], o4[k2i].x) : fminf(v[k2i*4+0], o4[k2i].x);
                    v[k2i*4+1] = keep_max ? fmaxf(v[k2i*4+1], o4[k2i].y) : fminf(v[k2i*4+1], o4[k2i].y);
                    v[k2i*4+2] = keep_max ? fmaxf(v[k2i*4+2], o4[k2i].z) : fminf(v[k2i*4+2], o4[k2i].z);
                    v[k2i*4+3] = keep_max ? fmaxf(v[k2i*4+3], o4[k2i].w) : fminf(v[k2i*4+3], o4[k2i].w);
                }
            } else if (j >= 16) {
                // ---- DPP quad exchange (VALU pipe): jl = 1 or 2 ----
                const int jl = j >> 4;
                const bool upper = (lane & jl) != 0;
                const bool dir0  = (lane & (kk >> 4)) == 0;
                const bool keep_max = dir0 ^ upper;
                float o[16];
                #pragma unroll
                for (int r = 0; r < 16; ++r)
                    o[r] = (jl == 1) ? dpp_perm<QP_XOR1>(v[r]) : dpp_perm<QP_XOR2>(v[r]);
                #pragma unroll
                for (int r = 0; r < 16; ++r)
                    v[r] = keep_max ? fmaxf(v[r], o[r]) : fminf(v[r], o[r]);
            } else {
                #pragma unroll
                for (int ra = 0; ra < 16; ++ra) {
                    if ((ra & j) == 0) {
                        const int rb = ra | j;
                        const bool dir0 = (kk >= 16) ? ((lane & (kk >> 4)) == 0) : ((ra & kk) == 0);
                        float aa = v[ra], bb = v[rb];
                        float mx = fmaxf(aa, bb), mn = fminf(aa, bb);
                        v[ra] = dir0 ? mx : mn;
                        v[rb] = dir0 ? mn : mx;
                    }
                }
            }
        }
    }

    // ranks = round(linspace(1,575,115)) == 1 + 5i + floor(2i/57) + (2i%57>=29)
    #pragma unroll
    for (int r = 0; r < 16; ++r) {
        const int pos = lane * 16 + r;
        const int rr0 = (int)((float)pos * 0.1993f);
        #pragma unroll
        for (int dd = -1; dd <= 2; ++dd) {
            const int cand = rr0 + dd;
            if (cand >= 0 && cand < 115) {
                const int ti = 2 * cand;
                const int rk = 1 + 5 * cand + ti / 57 + ((ti % 57) >= 29 ? 1 : 0);
                if (rk == pos) rankbuf[cand * 4 + wv] = v[r];
            }
        }
    }
    __syncthreads();
    if (t < 115) {
        float4 o = make_float4(rankbuf[t * 4 + 0], rankbuf[t * 4 + 1],
                               rankbuf[t * 4 + 2], rankbuf[t * 4 + 3]);
        *(float4*)&out[(size_t)b * 66240 + (size_t)t * 576 + q0] = o;
    }
}

extern "C" void kernel_launch(void* const* d_in, const int* in_sizes, int n_in,
                              void* d_out, int out_size, void* d_ws, size_t ws_size,
                              hipStream_t stream) {
    const float* x = (const float*)d_in[0];   // [8,64,64,64] fp32
    float* out = (float*)d_out;               // [8,115,24,24] fp32
    float* xp  = (float*)d_ws;                // [8,64,576] = 294912 floats
    float* ipn = xp + 294912;                 // [8,576] inverse norms

    k1<<<dim3(512),  dim3(512), 0, stream>>>(x, xp);
    k2<<<dim3(8),    dim3(576), 0, stream>>>(xp, ipn);
    k3<<<dim3(1152), dim3(256), 0, stream>>>(xp, ipn, out);
}

// Round 12
// 122.523 us; speedup vs baseline: 1.0577x; 1.0577x over previous
//
#include <hip/hip_runtime.h>
#include <math.h>
#include <float.h>

// b=8, c=64, H=W=64, KS=8 -> P = 57*57 = 3249.
// Stage 1 per (b,c): G[m,n] = <patch_m, patch_n> over P; corr = G/(sqrt(diag)sqrt(diag)P);
//   sort 64 m per column n desc; ranks {1,9,16,24,32,40,48,55,63} -> xp[b,c,576].
// Stage 2 per b: corr2[p,q] = sum_c Xn[c,p]Xn[c,q]/64; sort 576 p per q desc; 115 ranks.
//
// R12: k3 sort rebuilt as EXACT-576 monotone-mirror bitonic, layout idx = r*64+lane
//      (r = 0..8 registers, 576 = 9*64). In the mirror variant (first stage of each
//      kk pairs i <-> i^(kk-1), all comparators max-to-lower-index) virtual -inf pads
//      at idx>=576 never move, so every comparator touching r>=9 is statically
//      skipped: no pad registers, no exchange buffer, no wave_barrier, ~17% fewer
//      comparator ops and 9-vs-16 values per cross-lane stage. k1/k2 = R9 exact.

#define IMGS 65

// ---- DPP helpers (compile-time ctrl; LDS-pipe-free cross-lane) ----
template<int CTRL, int RM>
__device__ __forceinline__ float dpp_add(float x) {
    int o = __builtin_amdgcn_update_dpp(0, __float_as_int(x), CTRL, RM, 0xf, true);
    return x + __int_as_float(o);
}
// inclusive wave64 prefix sum
__device__ __forceinline__ float wscan_add(float x) {
    x = dpp_add<0x111, 0xf>(x);
    x = dpp_add<0x112, 0xf>(x);
    x = dpp_add<0x114, 0xf>(x);
    x = dpp_add<0x118, 0xf>(x);
    x = dpp_add<0x142, 0xa>(x);
    x = dpp_add<0x143, 0xc>(x);
    return x;
}
template<int CTRL>
__device__ __forceinline__ float dpp_perm(float x) {
    int o = __builtin_amdgcn_update_dpp(__float_as_int(x), __float_as_int(x), CTRL, 0xf, 0xf, false);
    return __int_as_float(o);
}
#define QP_XOR1 0xB1   // quad_perm [1,0,3,2]
#define QP_XOR2 0x4E   // quad_perm [2,3,0,1]
#define QP_XOR3 0x1B   // quad_perm [3,2,1,0]

__host__ __device__ constexpr int offF(int dj) { return dj * (17 - dj) / 2; }       // 36
__host__ __device__ constexpr int offB(int dj) { return (dj - 1) * (16 - dj) / 2; } // 28

// ---------------- k1: fused stage-1, pair-symmetric, canonical-G (R9 exact) ----------
// grid = 512 (bc), block = 512 (8 waves; wave wv handles row-shift d = wv)
__global__ __launch_bounds__(512) void k1(const float* __restrict__ x,
                                          float* __restrict__ xp) {
    __shared__ float img[64 * IMGS];   // 16.6 KB
    __shared__ float G[64 * IMGS];     // canonical: G[m*65+n], m<=n

    const int t = threadIdx.x;
    const int bc = blockIdx.x;
    const float* src = x + (size_t)bc * 4096;

    #pragma unroll
    for (int k = 0; k < 2; ++k) {
        int i4 = t + k * 512;
        float4 v = ((const float4*)src)[i4];
        int fl = i4 * 4, row = fl >> 6, col = fl & 63;
        float* dd = &img[row * IMGS + col];
        dd[0] = v.x; dd[1] = v.y; dd[2] = v.z; dd[3] = v.w;
    }
    __syncthreads();

    const int wv = t >> 6, lane = t & 63;
    const int d = wv;                            // 0..7
    const int a = lane;
    const bool av = (a + d <= 63);
    const int a1 = min(a + d, 63);
    const float* r0 = &img[a * IMGS];
    const float* r1 = &img[a1 * IMGS];

    // ---- FMA phase: wf[k]=sum_{u<57} r0[u]*r1[u+k], wb[k]=sum r1[u]*r0[u+k] ----
    float wf[8] = {0,0,0,0,0,0,0,0}, wb[8] = {0,0,0,0,0,0,0,0};
    float sf[8], sb[8], hf[7], hb[7];
    #pragma unroll
    for (int k = 0; k < 7; ++k) { sf[k] = r1[k]; sb[k] = r0[k]; hf[k] = sf[k]; hb[k] = sb[k]; }
    #pragma unroll
    for (int c = 0; c < 7; ++c) {
        #pragma unroll
        for (int j = 0; j < 8; ++j) {
            const int u = c * 8 + j;
            sf[(j + 7) & 7] = r1[u + 7];
            sb[(j + 7) & 7] = r0[u + 7];
            const float f0 = sb[j & 7];          // r0[u]
            const float g0 = sf[j & 7];          // r1[u]
            #pragma unroll
            for (int k = 0; k < 8; ++k) wf[k] = fmaf(f0, sf[(j + k) & 7], wf[k]);
            #pragma unroll
            for (int k = 1; k < 8; ++k) wb[k] = fmaf(g0, sb[(j + k) & 7], wb[k]);
        }
    }
    {   // u = 56
        sf[7] = r1[63]; sb[7] = r0[63];
        const float f0 = sb[0], g0 = sf[0];
        #pragma unroll
        for (int k = 0; k < 8; ++k) wf[k] = fmaf(f0, sf[k], wf[k]);
        #pragma unroll
        for (int k = 1; k < 8; ++k) wb[k] = fmaf(g0, sb[k], wb[k]);
    }
    // tails: sf[k] = r1[56+k], sb[k] = r0[56+k]; heads: hf/hb

    const float msk = av ? 1.0f : 0.0f;
    const bool wr = (lane >= 56) && (lane <= 63 - d);
    const int ki = lane - 56;

    // ======== FORWARD set ========
    {
        float Wf[36];
        #pragma unroll
        for (int dj = 0; dj < 8; ++dj) {
            float a0 = wf[dj];
            Wf[offF(dj)] = a0;
            #pragma unroll
            for (int st = 1; st < 8 - dj; ++st) {
                a0 += sb[st] * sf[st + dj] - hb[st - 1] * hf[st - 1 + dj];
                Wf[offF(dj) + st] = a0;
            }
        }
        #pragma unroll
        for (int i = 0; i < 36; ++i) Wf[i] = wscan_add(Wf[i] * msk);
        #pragma unroll
        for (int dj = 0; dj < 8; ++dj) {
            float su[8], S[8];
            #pragma unroll
            for (int st = 0; st < 8 - dj; ++st) su[st] = __shfl_up(Wf[offF(dj) + st], 57, 64);
            #pragma unroll
            for (int st = 0; st < 8 - dj; ++st)
                S[st] = Wf[offF(dj) + st] - (lane >= 57 ? su[st] : 0.0f);
            #pragma unroll
            for (int st = 0; st < 8 - dj; ++st)
                if (wr) G[(ki * 8 + st) * IMGS + ((ki + d) * 8 + st + dj)] = S[st];
        }
    }
    // ======== BACKWARD set ========
    if (d > 0) {
        float Wb[28];
        #pragma unroll
        for (int dj = 1; dj < 8; ++dj) {
            float a0 = wb[dj];
            Wb[offB(dj)] = a0;
            #pragma unroll
            for (int st = 1; st < 8 - dj; ++st) {
                a0 += sf[st] * sb[st + dj] - hf[st - 1] * hb[st - 1 + dj];
                Wb[offB(dj) + st] = a0;
            }
        }
        #pragma unroll
        for (int i = 0; i < 28; ++i) Wb[i] = wscan_add(Wb[i] * msk);
        #pragma unroll
        for (int dj = 1; dj < 8; ++dj) {
            float su[7], S[7];
            #pragma unroll
            for (int st = 0; st < 8 - dj; ++st) su[st] = __shfl_up(Wb[offB(dj) + st], 57, 64);
            #pragma unroll
            for (int st = 0; st < 8 - dj; ++st)
                S[st] = Wb[offB(dj) + st] - (lane >= 57 ? su[st] : 0.0f);
            #pragma unroll
            for (int st = 0; st < 8 - dj; ++st)
                if (wr) G[(ki * 8 + st + dj) * IMGS + ((ki + d) * 8 + st)] = S[st];
        }
    }
    __syncthreads();

    // ---- normalize + batched sort64 (wave wv: columns wv*8..wv*8+7) ----
    const int m = lane;
    const float invm = 1.0f / fmaxf(sqrtf(G[m * 66]), 1e-12f);
    const float sc = 1.0f / 3249.0f;
    const int c0 = wv * 8;
    float v[8];
    #pragma unroll
    for (int cc = 0; cc < 8; ++cc) {
        const int col = c0 + cc;
        const int addr = (m <= col) ? m * IMGS + col : col * IMGS + m;   // symmetric read
        const float invc = __shfl(invm, col, 64);
        v[cc] = G[addr] * invm * invc * sc;
    }
    #pragma unroll
    for (int kk = 2; kk <= 64; kk <<= 1) {
        #pragma unroll
        for (int j = kk >> 1; j > 0; j >>= 1) {
            const bool upper = (lane & j) != 0;
            const bool dir0  = (lane & kk) == 0;
            const bool keep_max = dir0 ^ upper;
            float o[8];
            #pragma unroll
            for (int cc = 0; cc < 8; ++cc) {
                if (j == 1)      o[cc] = dpp_perm<QP_XOR1>(v[cc]);
                else if (j == 2) o[cc] = dpp_perm<QP_XOR2>(v[cc]);
                else             o[cc] = __shfl_xor(v[cc], j, 64);
            }
            #pragma unroll
            for (int cc = 0; cc < 8; ++cc)
                v[cc] = keep_max ? fmaxf(v[cc], o[cc]) : fminf(v[cc], o[cc]);
        }
    }
    // ranks2 = {1,9,16,24,32,40,48,55,63}
    int ridx = -1;
    if      (lane ==  1) ridx = 0; else if (lane ==  9) ridx = 1; else if (lane == 16) ridx = 2;
    else if (lane == 24) ridx = 3; else if (lane == 32) ridx = 4; else if (lane == 40) ridx = 5;
    else if (lane == 48) ridx = 6; else if (lane == 55) ridx = 7; else if (lane == 63) ridx = 8;
    if (ridx >= 0) {
        float* dst = xp + (size_t)bc * 576 + ridx * 64 + c0;
        *(float4*)&dst[0] = make_float4(v[0], v[1], v[2], v[3]);
        *(float4*)&dst[4] = make_float4(v[4], v[5], v[6], v[7]);
    }
}

// ---------------- k2: stage-2 inverse channel norms ----------------
// grid = 8, block = 576
__global__ __launch_bounds__(576) void k2(const float* __restrict__ xp,
                                          float* __restrict__ ipn) {
    const int b = blockIdx.x, p = threadIdx.x;
    const float* base = xp + (size_t)b * 36864 + p;
    float s = 0.f;
    #pragma unroll
    for (int c = 0; c < 64; ++c) { float v = base[c * 576]; s = fmaf(v, v, s); }
    ipn[b * 576 + p] = 1.0f / fmaxf(sqrtf(s), 1e-12f);
}

// ---- one monotone-mirror bitonic stage on v[0..8], layout idx = r*64 + lane ----
// Comparator (i, i^M), max kept at lower index. HB = the index bit that separates
// lower/upper side of each pair. Pairs touching r>=9 (virtual -inf pads) skipped.
template<int M, int HB>
__device__ __forceinline__ void bstage(float* v, int lane) {
    const int mreg = M >> 6, mlane = M & 63;
    float o[9];
    #pragma unroll
    for (int r = 0; r < 9; ++r) {
        const int pr = r ^ mreg;
        if (pr <= 8) {
            if      (mlane == 0) o[r] = v[pr];
            else if (mlane == 1) o[r] = dpp_perm<QP_XOR1>(v[pr]);
            else if (mlane == 2) o[r] = dpp_perm<QP_XOR2>(v[pr]);
            else if (mlane == 3) o[r] = dpp_perm<QP_XOR3>(v[pr]);
            else                 o[r] = __shfl_xor(v[pr], mlane, 64);
        }
    }
    #pragma unroll
    for (int r = 0; r < 9; ++r) {
        const int pr = r ^ mreg;
        if (pr <= 8) {
            bool lower;
            if (HB >= 64) lower = ((r & (HB >> 6)) == 0);     // compile-time per r
            else          lower = ((lane & HB) == 0);         // per-lane
            v[r] = lower ? fmaxf(v[r], o[r]) : fminf(v[r], o[r]);
        }
    }
}

// ---------------- k3: stage-2 corr columns + exact-576 register bitonic + ranks ------
// grid = 8*144 (4 q per block; wave wv sorts column q0+wv), block = 256
__global__ __launch_bounds__(256) void k3(const float* __restrict__ xp,
                                          const float* __restrict__ ipn,
                                          float* __restrict__ out) {
    __shared__ __align__(16) float sbuf[4][580];
    __shared__ float rankbuf[115 * 4];
    const int t = threadIdx.x;
    const int b = blockIdx.x / 144, qg = blockIdx.x % 144;
    const int q0 = qg * 4;
    const float* __restrict__ xb  = xp  + (size_t)b * 36864;
    const float* __restrict__ ipb = ipn + (size_t)b * 576;

    // ---- phase 1: normalized corr2 columns for 4 q's ----
    {
        float iq[4];
        #pragma unroll
        for (int qq = 0; qq < 4; ++qq) iq[qq] = ipb[q0 + qq] * 0.015625f;   // /64
        for (int p = t; p < 576; p += 256) {
            float a0 = 0.f, a1 = 0.f, a2 = 0.f, a3 = 0.f;
            #pragma unroll 8
            for (int c = 0; c < 64; ++c) {
                const float xv = xb[c * 576 + p];              // coalesced vector load
                const int qb = c * 576 + q0;
                a0 = fmaf(xv, xb[qb + 0], a0);                 // uniform -> scalar loads
                a1 = fmaf(xv, xb[qb + 1], a1);
                a2 = fmaf(xv, xb[qb + 2], a2);
                a3 = fmaf(xv, xb[qb + 3], a3);
            }
            const float ip = ipb[p];
            sbuf[0][p] = a0 * ip * iq[0];
            sbuf[1][p] = a1 * ip * iq[1];
            sbuf[2][p] = a2 * ip * iq[2];
            sbuf[3][p] = a3 * ip * iq[3];
        }
    }
    __syncthreads();

    // ---- phase 2: wave wv sorts its column, idx = r*64 + lane, r = 0..8 ----
    const int wv = t >> 6, lane = t & 63;
    float v[9];
    {
        const float* sb2 = &sbuf[wv][0];
        #pragma unroll
        for (int r = 0; r < 9; ++r) v[r] = sb2[r * 64 + lane];
    }

    // monotone-mirror bitonic, descending, N=1024 with statically-skipped pads
    bstage<1, 1>(v, lane);                                                   // kk=2
    bstage<3, 2>(v, lane);    bstage<1, 1>(v, lane);                         // kk=4
    bstage<7, 4>(v, lane);    bstage<2, 2>(v, lane);  bstage<1, 1>(v, lane); // kk=8
    bstage<15, 8>(v, lane);   bstage<4, 4>(v, lane);  bstage<2, 2>(v, lane); // kk=16
    bstage<1, 1>(v, lane);
    bstage<31, 16>(v, lane);  bstage<8, 8>(v, lane);  bstage<4, 4>(v, lane); // kk=32
    bstage<2, 2>(v, lane);    bstage<1, 1>(v, lane);
    bstage<63, 32>(v, lane);  bstage<16, 16>(v, lane); bstage<8, 8>(v, lane); // kk=64
    bstage<4, 4>(v, lane);    bstage<2, 2>(v, lane);  bstage<1, 1>(v, lane);
    bstage<127, 64>(v, lane); bstage<32, 32>(v, lane); bstage<16, 16>(v, lane); // kk=128
    bstage<8, 8>(v, lane);    bstage<4, 4>(v, lane);  bstage<2, 2>(v, lane);
    bstage<1, 1>(v, lane);
    bstage<255, 128>(v, lane); bstage<64, 64>(v, lane); bstage<32, 32>(v, lane); // kk=256
    bstage<16, 16>(v, lane);  bstage<8, 8>(v, lane);  bstage<4, 4>(v, lane);
    bstage<2, 2>(v, lane);    bstage<1, 1>(v, lane);
    bstage<511, 256>(v, lane); bstage<128, 128>(v, lane); bstage<64, 64>(v, lane); // kk=512
    bstage<32, 32>(v, lane);  bstage<16, 16>(v, lane); bstage<8, 8>(v, lane);
    bstage<4, 4>(v, lane);    bstage<2, 2>(v, lane);  bstage<1, 1>(v, lane);
    bstage<1023, 512>(v, lane); bstage<256, 256>(v, lane); bstage<128, 128>(v, lane); // kk=1024
    bstage<64, 64>(v, lane);  bstage<32, 32>(v, lane); bstage<16, 16>(v, lane);
    bstage<8, 8>(v, lane);    bstage<4, 4>(v, lane);  bstage<2, 2>(v, lane);
    bstage<1, 1>(v, lane);

    // ranks = round(linspace(1,575,115)) == 1 + 5i + floor(2i/57) + (2i%57>=29)
    #pragma unroll
    for (int r = 0; r < 9; ++r) {
        const int pos = r * 64 + lane;
        const int rr0 = (int)((float)pos * 0.1993f);
        #pragma unroll
        for (int dd = -1; dd <= 2; ++dd) {
            const int cand = rr0 + dd;
            if (cand >= 0 && cand < 115) {
                const int ti = 2 * cand;
                const int rk = 1 + 5 * cand + ti / 57 + ((ti % 57) >= 29 ? 1 : 0);
                if (rk == pos) rankbuf[cand * 4 + wv] = v[r];
            }
        }
    }
    __syncthreads();
    if (t < 115) {
        float4 o = make_float4(rankbuf[t * 4 + 0], rankbuf[t * 4 + 1],
                               rankbuf[t * 4 + 2], rankbuf[t * 4 + 3]);
        *(float4*)&out[(size_t)b * 66240 + (size_t)t * 576 + q0] = o;
    }
}

extern "C" void kernel_launch(void* const* d_in, const int* in_sizes, int n_in,
                              void* d_out, int out_size, void* d_ws, size_t ws_size,
                              hipStream_t stream) {
    const float* x = (const float*)d_in[0];   // [8,64,64,64] fp32
    float* out = (float*)d_out;               // [8,115,24,24] fp32
    float* xp  = (float*)d_ws;                // [8,64,576] = 294912 floats
    float* ipn = xp + 294912;                 // [8,576] inverse norms

    k1<<<dim3(512),  dim3(512), 0, stream>>>(x, xp);
    k2<<<dim3(8),    dim3(576), 0, stream>>>(xp, ipn);
    k3<<<dim3(1152), dim3(256), 0, stream>>>(xp, ipn, out);
}